// Round 8
// baseline (290.624 us; speedup 1.0000x reference)
//
#include <hip/hip_runtime.h>

// CausalAttention2d: B=2, C=512, H=W=64 (N=4096 tokens), E=512, nh=8, hd=64.
// Inputs fp32 (runtime-detected; bf16 path kept defensively). Pipeline:
//   detect -> wcvt -> transpose -> gemm3 (fused QKV) -> zero -> attn -> norm.
// Round 8: (a) key-split flash attention: constant-shift softmax makes
// partial (O,l) LINEAR, so q-tile p is computed by two equal-size blocks
// (key-tiles [0,p] and [p+1,2p+1]) that atomicAdd fp32 partials into d_out
// and an l-buffer; grid 512->1024 => 4 blocks/CU, 4 waves/SIMD (was 2 -
// r7 was latency-bound, both pipes <45%). (b) PV at K=32 via permuted QK
// A-rows: S^T per lane holds keys quad*8+{0..7} = exact 16x16x32 B-frag;
// PV MFMA count halves, V LDS reads become b128. (c) rotate-swizzle LDS
// (slot=(gran+row)&7, SK=72) -> conflict-free banks for all patterns.
// (d) QKV gemms fused into one launch.

typedef __bf16 bf16;
typedef __attribute__((ext_vector_type(8))) __bf16 bf16x8;
typedef __attribute__((ext_vector_type(4))) float floatx4;

#define B_ 2
#define Cc 512
#define Nn 4096
#define Ee 512
#define NH 8
#define HD 64

#define QSCALE 0.1803368801111204f   // log2(e)/8, folded into Q
#define SHIFT 11.541560327111707f    // 8*log2(e): p = 2^(s - SHIFT)

// ---------------------------------------------------------------- detector
__global__ __launch_bounds__(64) void detect_dtype(
    const unsigned short* __restrict__ w, int* __restrict__ flag) {
  bool bad = false;
#pragma unroll
  for (int i = 0; i < 16; ++i) {
    unsigned u = w[threadIdx.x * 16 + i];
    float v = __uint_as_float(u << 16);
    bad |= !(v > -1024.f && v < 1024.f);  // catches big / inf / NaN
  }
  unsigned long long b = __ballot(bad);
  if (threadIdx.x == 0) *flag = (b != 0ull) ? 1 : 0;
}

// ---------------------------------------------------------------- wcvt
#define WSEG 262144          // 512*512
#define WTOT 787968          // 3*WSEG + 3*512
__global__ __launch_bounds__(256) void wcvt(
    const float* __restrict__ Wq, const float* __restrict__ Wk,
    const float* __restrict__ Wv, const float* __restrict__ bq,
    const float* __restrict__ bk, const float* __restrict__ bv,
    bf16* __restrict__ out, const int* __restrict__ flagp) {
  if (!*flagp) return;
  int idx = (blockIdx.x * 256 + threadIdx.x) * 8;
  if (idx >= WTOT) return;
  const float* src;
  int off;
  if (idx < WSEG)            { src = Wq; off = idx; }
  else if (idx < 2 * WSEG)   { src = Wk; off = idx - WSEG; }
  else if (idx < 3 * WSEG)   { src = Wv; off = idx - 2 * WSEG; }
  else if (idx < 3 * WSEG + 512)  { src = bq; off = idx - 3 * WSEG; }
  else if (idx < 3 * WSEG + 1024) { src = bk; off = idx - 3 * WSEG - 512; }
  else                            { src = bv; off = idx - 3 * WSEG - 1024; }
  float4 a = *(const float4*)(src + off);
  float4 c = *(const float4*)(src + off + 4);
  union { bf16 h[8]; bf16x8 v; } u;
  u.h[0] = (bf16)a.x; u.h[1] = (bf16)a.y; u.h[2] = (bf16)a.z; u.h[3] = (bf16)a.w;
  u.h[4] = (bf16)c.x; u.h[5] = (bf16)c.y; u.h[6] = (bf16)c.z; u.h[7] = (bf16)c.w;
  *(bf16x8*)(out + idx) = u.v;
}

// load 8 consecutive elements as bf16x8 from bf16 (f32=0) or fp32 (f32=1).
__device__ __forceinline__ bf16x8 load8e(const void* base, size_t eidx, int f32) {
  if (!f32) return *(const bf16x8*)((const bf16*)base + eidx);
  const float* f = (const float*)base + eidx;
  float4 a = *(const float4*)f;
  float4 c = *(const float4*)(f + 4);
  union { bf16 h[8]; bf16x8 v; } u;
  u.h[0] = (bf16)a.x; u.h[1] = (bf16)a.y; u.h[2] = (bf16)a.z; u.h[3] = (bf16)a.w;
  u.h[4] = (bf16)c.x; u.h[5] = (bf16)c.y; u.h[6] = (bf16)c.z; u.h[7] = (bf16)c.w;
  return u.v;
}

// ---------------------------------------------------------------- transpose
__global__ __launch_bounds__(256) void transpose_k(
    const void* __restrict__ X0, const void* __restrict__ X1,
    bf16* __restrict__ T0, bf16* __restrict__ T1,
    const int* __restrict__ flagp) {
  const int f32 = *flagp;
  __shared__ __align__(16) bf16 T[64 * 64];
  const int z = blockIdx.z;
  const int bb = z & 1;
  const void* src = (z >> 1) ? X1 : X0;
  bf16* dst = (z >> 1) ? T1 : T0;
  const int n0 = blockIdx.x * 64, c0 = blockIdx.y * 64;
  const int t = threadIdx.x;
  const size_t sbase = ((size_t)bb * Cc + c0) * (size_t)Nn + n0;

#pragma unroll
  for (int it = 0; it < 2; ++it) {
    int task = t + it * 256;            // 512 tasks: 64 c-rows x 8 n-granules
    int crow = task >> 3, gr = task & 7;
    bf16x8 v = load8e(src, sbase + (size_t)crow * Nn + gr * 8, f32);
    int slot = gr ^ (crow & 7);
    *(bf16x8*)&T[crow * 64 + slot * 8] = v;
  }
  __syncthreads();
  const int nrow = t & 63, cp = t >> 6;
  bf16* db = dst + ((size_t)bb * Nn + n0 + nrow) * Cc + c0;
#pragma unroll
  for (int it = 0; it < 2; ++it) {
    int cg = cp * 2 + it;               // c-granule 0..7
    union { bf16 h[8]; bf16x8 v; } u;
#pragma unroll
    for (int j = 0; j < 8; ++j) {
      int c = cg * 8 + j;
      int slot = (nrow >> 3) ^ (c & 7);
      u.h[j] = T[c * 64 + slot * 8 + (nrow & 7)];
    }
    *(bf16x8*)(db + cg * 8) = u.v;
  }
}

// ---------------------------------------------------------------- gemm3
// Fused Q/K/V projection. blockIdx.z: 0,1 = Q(b); 2,3 = K(b); 4,5 = V(b).
// Out[m][n] = (sum_k A[m][k]*Bt[n][k] + bias) * scaleOut, K=512.
// Double-buffered LDS, one barrier per K-step, register prefetch.
__global__ __launch_bounds__(256) void gemm3(
    const bf16* __restrict__ Xtq, const bf16* __restrict__ Xtk,
    const void* __restrict__ Wq0, const bf16* __restrict__ Wqb,
    const void* __restrict__ Wk0, const bf16* __restrict__ Wkb,
    const void* __restrict__ Wv0, const bf16* __restrict__ Wvb,
    const void* __restrict__ bq0, const bf16* __restrict__ bqb,
    const void* __restrict__ bk0, const bf16* __restrict__ bkb,
    const void* __restrict__ bv0, const bf16* __restrict__ bvb,
    bf16* __restrict__ Qt, bf16* __restrict__ Kt, bf16* __restrict__ Vh,
    const int* __restrict__ flagp) {
  const int f32 = *flagp;
  const int op = blockIdx.z >> 1, b = blockIdx.z & 1;
  const bf16 *A, *Bt, *bias;
  bf16* Out;
  long sAb, sBb, sOb;
  int Nq, biasOnM, m0, n0;
  float scaleOut;
  if (op == 0) {
    A = Xtq; sAb = (long)Nn * Cc;
    Bt = f32 ? Wqb : (const bf16*)Wq0; sBb = 0;
    bias = f32 ? bqb : (const bf16*)bq0;
    Out = Qt; sOb = (long)Nn * Ee; Nq = Ee; biasOnM = 0; scaleOut = QSCALE;
    m0 = blockIdx.x * 128; n0 = blockIdx.y * 64;
  } else if (op == 1) {
    A = Xtk; sAb = (long)Nn * Cc;
    Bt = f32 ? Wkb : (const bf16*)Wk0; sBb = 0;
    bias = f32 ? bkb : (const bf16*)bk0;
    Out = Kt; sOb = (long)Nn * Ee; Nq = Ee; biasOnM = 0; scaleOut = 1.0f;
    m0 = blockIdx.x * 128; n0 = blockIdx.y * 64;
  } else {
    A = f32 ? Wvb : (const bf16*)Wv0; sAb = 0;
    Bt = Xtk; sBb = (long)Nn * Cc;
    bias = f32 ? bvb : (const bf16*)bv0;
    Out = Vh; sOb = (long)Ee * Nn; Nq = Nn; biasOnM = 1; scaleOut = 1.0f;
    m0 = (blockIdx.x >> 3) * 128;
    n0 = (blockIdx.y * 8 + (blockIdx.x & 7)) * 64;
  }
  constexpr int K = 512;
  constexpr int SA = 40;
  __shared__ __align__(16) bf16 As[2][128 * SA];
  __shared__ __align__(16) bf16 Bs[2][64 * SA];
  const int tid = threadIdx.x;
  const int lane = tid & 63, wave = tid >> 6;
  const int quad = lane >> 4, lm = lane & 15;
  const bf16* Ab = A + (size_t)b * sAb;
  const bf16* Bb = Bt + (size_t)b * sBb;
  bf16* Ob = Out + (size_t)b * sOb;

  const int arow = tid >> 2, ag = tid & 3;

  floatx4 acc[2][4];
#pragma unroll
  for (int i = 0; i < 2; ++i)
#pragma unroll
    for (int j = 0; j < 4; ++j) acc[i][j] = (floatx4){0.f, 0.f, 0.f, 0.f};

  bf16x8 a0 = *(const bf16x8*)(Ab + (size_t)(m0 + arow) * K + ag * 8);
  bf16x8 a1 = *(const bf16x8*)(Ab + (size_t)(m0 + 64 + arow) * K + ag * 8);
  bf16x8 b0 = *(const bf16x8*)(Bb + (size_t)(n0 + arow) * K + ag * 8);
  *(bf16x8*)&As[0][arow * SA + ag * 8] = a0;
  *(bf16x8*)&As[0][(64 + arow) * SA + ag * 8] = a1;
  *(bf16x8*)&Bs[0][arow * SA + ag * 8] = b0;
  __syncthreads();

  for (int kk = 0; kk < 16; ++kk) {
    const int c = kk & 1;
    const bool more = kk < 15;
    if (more) {
      int k0 = (kk + 1) * 32;
      a0 = *(const bf16x8*)(Ab + (size_t)(m0 + arow) * K + k0 + ag * 8);
      a1 = *(const bf16x8*)(Ab + (size_t)(m0 + 64 + arow) * K + k0 + ag * 8);
      b0 = *(const bf16x8*)(Bb + (size_t)(n0 + arow) * K + k0 + ag * 8);
    }
    bf16x8 af[2], bfr[4];
#pragma unroll
    for (int mf = 0; mf < 2; ++mf) {
      int r = wave * 32 + mf * 16 + lm;
      af[mf] = *(const bf16x8*)&As[c][r * SA + quad * 8];
    }
#pragma unroll
    for (int nf = 0; nf < 4; ++nf) {
      int r = nf * 16 + lm;
      bfr[nf] = *(const bf16x8*)&Bs[c][r * SA + quad * 8];
    }
    if (more) {
      *(bf16x8*)&As[c ^ 1][arow * SA + ag * 8] = a0;
      *(bf16x8*)&As[c ^ 1][(64 + arow) * SA + ag * 8] = a1;
      *(bf16x8*)&Bs[c ^ 1][arow * SA + ag * 8] = b0;
    }
#pragma unroll
    for (int mf = 0; mf < 2; ++mf)
#pragma unroll
      for (int nf = 0; nf < 4; ++nf)
        acc[mf][nf] = __builtin_amdgcn_mfma_f32_16x16x32_bf16(
            af[mf], bfr[nf], acc[mf][nf], 0, 0, 0);
    __syncthreads();
  }

#pragma unroll
  for (int mf = 0; mf < 2; ++mf) {
#pragma unroll
    for (int nf = 0; nf < 4; ++nf) {
      int col = n0 + nf * 16 + lm;
      float bn = biasOnM ? 0.f : (float)bias[col];
#pragma unroll
      for (int r = 0; r < 4; ++r) {
        int rowg = m0 + wave * 32 + mf * 16 + quad * 4 + r;
        float bv = biasOnM ? (float)bias[rowg] : bn;
        Ob[(size_t)rowg * Nq + col] = (bf16)((acc[mf][nf][r] + bv) * scaleOut);
      }
    }
  }
}

// ---------------------------------------------------------------- zero_ws
// Blocks [0,4096): zero O accumulator (d_out, 16MB, only when fp32).
// Blocks [4096,4160): zero l accumulator (256KB, always).
__global__ __launch_bounds__(256) void zero_ws(
    float* __restrict__ O, float* __restrict__ lbuf,
    const int* __restrict__ flagp) {
  int bid = blockIdx.x;
  if (bid < 4096) {
    if (!*flagp) return;
    size_t i = ((size_t)bid * 256 + threadIdx.x);
    ((float4*)O)[i] = (float4){0.f, 0.f, 0.f, 0.f};
  } else {
    size_t i = ((size_t)(bid - 4096) * 256 + threadIdx.x);
    ((float4*)lbuf)[i] = (float4){0.f, 0.f, 0.f, 0.f};
  }
}

// ---------------------------------------------------------------- attention
// Grid (64, NH, B): bx -> (pair = bx>>1, chunk = bx&1), p = 31-pair (heavy
// first). Block = 4 waves x 32 q = 128 q-rows at q-tile p; chunk0 covers
// key-tiles [0,p], chunk1 [p+1,2p+1] (equal size). Partial (O,l) are linear
// under constant-shift softmax -> fp32 atomicAdd combine; normalize divides.
// Per 64-key tile: QK with permuted A-rows so S^T per lane = keys
// quad*8+{0..7} (16x16x32 PV B-frag, in-register); V reads b128. LDS
// rotate-swizzle slot=(gran+row)&7 on SK=72 -> conflict-free.
__global__ __launch_bounds__(256, 4) void attn(
    const bf16* __restrict__ Qt, const bf16* __restrict__ Kt,
    const bf16* __restrict__ Ve, void* __restrict__ Out,
    float* __restrict__ lbuf, const int* __restrict__ flagp) {
  const int f32 = *flagp;
  constexpr int SK = 72;
  __shared__ __align__(16) bf16 Ks[2][64 * SK];   // [buf][key][e]
  __shared__ __align__(16) bf16 Vs[2][64 * SK];   // [buf][d][key]
  const int tid = threadIdx.x, lane = tid & 63, w = tid >> 6;
  const int quad = lane >> 4, lm = lane & 15;
  const int b = blockIdx.z, h = blockIdx.y;
  const int pair = blockIdx.x >> 1, chunk = blockIdx.x & 1;
  const int p = 31 - pair;
  int kt0, ktend;
  if (f32) {
    kt0 = chunk ? p + 1 : 0;
    ktend = chunk ? 2 * p + 1 : p;
  } else {
    if (chunk) return;   // bf16 fallback: single block does the full range
    kt0 = 0;
    ktend = 2 * p + 1;
  }
  const int Q0 = p * 128;
  const int qbase = Q0 + w * 32;

  // Q B-frags (persistent): qf[qi][ks] = B[e=quad*8+j+ks*32][q=qi*16+lm]
  bf16x8 qf[2][2];
#pragma unroll
  for (int qi = 0; qi < 2; ++qi) {
    const bf16* qp =
        Qt + ((size_t)b * Nn + qbase + qi * 16 + lm) * Ee + h * HD + quad * 8;
    qf[qi][0] = *(const bf16x8*)qp;
    qf[qi][1] = *(const bf16x8*)(qp + 32);
  }
  floatx4 accO[2][4];
#pragma unroll
  for (int qi = 0; qi < 2; ++qi)
#pragma unroll
    for (int df = 0; df < 4; ++df) accO[qi][df] = (floatx4){0.f, 0.f, 0.f, 0.f};
  float lsum[2] = {0.f, 0.f};

  // staging: r0 = tid>>3 in [0,32), g = tid&7; rows r0 and r0+32
  const int r0 = tid >> 3, g = tid & 7;
  const int sslot = ((g + r0) & 7) * 8;           // rotate swizzle
  const bf16* kp0 = Kt + ((size_t)b * Nn + kt0 * 64 + r0) * Ee + h * HD + g * 8;
  const bf16* kp1 = kp0 + (size_t)32 * Ee;
  const bf16* vp0 = Ve + ((size_t)b * Ee + h * HD + r0) * Nn + kt0 * 64 + g * 8;
  const bf16* vp1 = vp0 + (size_t)32 * Nn;

  // QK A-row permutation base: key(C-row m=quad*4+r) = quad*8+4(f&1)+r(+32(f>>1))
  const int rbase = ((lm >> 2) << 3) | (lm & 3);

  // prologue: tile kt0 -> buf 0
  bf16x8 ka = *(const bf16x8*)kp0;
  bf16x8 kb = *(const bf16x8*)kp1;
  bf16x8 va = *(const bf16x8*)vp0;
  bf16x8 vb = *(const bf16x8*)vp1;
  kp0 += (size_t)64 * Ee; kp1 += (size_t)64 * Ee;
  vp0 += 64; vp1 += 64;
  *(bf16x8*)&Ks[0][r0 * SK + sslot] = ka;
  *(bf16x8*)&Ks[0][(r0 + 32) * SK + sslot] = kb;
  *(bf16x8*)&Vs[0][r0 * SK + sslot] = va;
  *(bf16x8*)&Vs[0][(r0 + 32) * SK + sslot] = vb;
  __syncthreads();

#pragma unroll 1
  for (int kt = kt0; kt <= ktend; ++kt) {
    const int c = (kt - kt0) & 1;
    const int k0 = kt * 64;
    const bool more = kt < ktend;
    if (more) {                       // prefetch next tile (hidden under QK)
      ka = *(const bf16x8*)kp0;
      kb = *(const bf16x8*)kp1;
      va = *(const bf16x8*)vp0;
      vb = *(const bf16x8*)vp1;
      kp0 += (size_t)64 * Ee; kp1 += (size_t)64 * Ee;
      vp0 += 64; vp1 += 64;
    }
    const bool skip = k0 > qbase + 31;  // wave-uniform: tile fully masked

    bf16x8 pb[2][2];
    if (!skip) {
      // S^T = K Q^T with permuted A-rows
      floatx4 accS[2][4];
#pragma unroll
      for (int qi = 0; qi < 2; ++qi)
#pragma unroll
        for (int f = 0; f < 4; ++f) accS[qi][f] = (floatx4){0.f, 0.f, 0.f, 0.f};
#pragma unroll
      for (int ks = 0; ks < 2; ++ks)
#pragma unroll
        for (int f = 0; f < 4; ++f) {
          const int R = rbase + ((f & 1) << 2) + ((f >> 1) << 5);
          const int slot = (ks * 4 + quad + R) & 7;
          bf16x8 ak = *(const bf16x8*)&Ks[c][R * SK + slot * 8];
#pragma unroll
          for (int qi = 0; qi < 2; ++qi)
            accS[qi][f] = __builtin_amdgcn_mfma_f32_16x16x32_bf16(
                ak, qf[qi][ks], accS[qi][f], 0, 0, 0);
        }
      // softmax + pack: key = k0 + g2*32 + quad*8 + j; q = qbase+qi*16+lm
      const bool maskt = (k0 + 63 > qbase);
#pragma unroll
      for (int qi = 0; qi < 2; ++qi) {
        const int qg = qbase + qi * 16 + lm;
#pragma unroll
        for (int g2 = 0; g2 < 2; ++g2) {
          union { bf16 h8[8]; bf16x8 v; } u;
#pragma unroll
          for (int j = 0; j < 8; ++j) {
            float sv = accS[qi][g2 * 2 + (j >> 2)][j & 3];
            float pv = __builtin_exp2f(sv - SHIFT);
            if (maskt && (k0 + g2 * 32 + quad * 8 + j) > qg) pv = 0.f;
            lsum[qi] += pv;
            u.h8[j] = (bf16)pv;
          }
          pb[qi][g2] = u.v;
        }
      }
    }
    if (more) {                       // stage prefetched tile into other buf
      *(bf16x8*)&Ks[c ^ 1][r0 * SK + sslot] = ka;
      *(bf16x8*)&Ks[c ^ 1][(r0 + 32) * SK + sslot] = kb;
      *(bf16x8*)&Vs[c ^ 1][r0 * SK + sslot] = va;
      *(bf16x8*)&Vs[c ^ 1][(r0 + 32) * SK + sslot] = vb;
    }
    if (!skip) {
      // O^T += V^T P^T at K=32: A[d=df*16+lm][key=g2*32+quad*8+j] (b128)
#pragma unroll
      for (int g2 = 0; g2 < 2; ++g2)
#pragma unroll
        for (int df = 0; df < 4; ++df) {
          const int Rv = df * 16 + lm;
          const int slot = (g2 * 4 + quad + Rv) & 7;
          bf16x8 av = *(const bf16x8*)&Vs[c][Rv * SK + slot * 8];
#pragma unroll
          for (int qi = 0; qi < 2; ++qi)
            accO[qi][df] = __builtin_amdgcn_mfma_f32_16x16x32_bf16(
                av, pb[qi][g2], accO[qi][df], 0, 0, 0);
        }
    }
    __syncthreads();  // buf c reads done everywhere; buf c^1 fully staged
  }

  // l(q) split across the 4 quads -> reduce lanes lm+16k
#pragma unroll
  for (int qi = 0; qi < 2; ++qi) {
    lsum[qi] += __shfl_xor(lsum[qi], 16);
    lsum[qi] += __shfl_xor(lsum[qi], 32);
  }

  if (f32) {
    // partial combine: atomicAdd fp32 O and l (linear under constant shift)
    float* Oa = (float*)Out;
#pragma unroll
    for (int qi = 0; qi < 2; ++qi) {
      const int qg = qbase + qi * 16 + lm;
#pragma unroll
      for (int df = 0; df < 4; ++df)
#pragma unroll
        for (int r = 0; r < 4; ++r)
          atomicAdd(
              Oa + ((size_t)b * Ee + h * HD + df * 16 + quad * 4 + r) * Nn + qg,
              accO[qi][df][r]);
    }
    if (quad == 0) {
#pragma unroll
      for (int qi = 0; qi < 2; ++qi)
        atomicAdd(lbuf + ((size_t)b * NH + h) * Nn + qbase + qi * 16 + lm,
                  lsum[qi]);
    }
  } else {
    // bf16 fallback: chunk0 did the full range -> direct write
#pragma unroll
    for (int qi = 0; qi < 2; ++qi) {
      const float inv = 1.0f / lsum[qi];
      const int qg = qbase + qi * 16 + lm;
#pragma unroll
      for (int df = 0; df < 4; ++df)
#pragma unroll
        for (int r = 0; r < 4; ++r) {
          int d = h * HD + df * 16 + quad * 4 + r;
          ((bf16*)Out)[((size_t)b * Ee + d) * Nn + qg] =
              (bf16)(accO[qi][df][r] * inv);
        }
    }
  }
}

// ---------------------------------------------------------------- normalize
// out[b][e][n] = O[b][e][n] / l[b][e>>6][n]  (fp32 path only)
__global__ __launch_bounds__(256) void normalize(
    float* __restrict__ O, const float* __restrict__ lbuf,
    const int* __restrict__ flagp) {
  if (!*flagp) return;
  size_t idx = ((size_t)blockIdx.x * 256 + threadIdx.x) * 4;
  int bh = (int)(idx >> 18);          // b*NH + h
  int n = (int)(idx & 4095);
  float4 o = *(float4*)(O + idx);
  float4 lv = *(const float4*)(lbuf + ((size_t)bh << 12) + n);
  o.x /= lv.x; o.y /= lv.y; o.z /= lv.z; o.w /= lv.w;
  *(float4*)(O + idx) = o;
}

// ---------------------------------------------------------------- launch
extern "C" void kernel_launch(void* const* d_in, const int* in_sizes, int n_in,
                              void* d_out, int out_size, void* d_ws,
                              size_t ws_size, hipStream_t stream) {
  const void* q  = d_in[0];
  const void* k  = d_in[1];
  const void* Wq = d_in[2];
  const void* bq = d_in[3];
  const void* Wk = d_in[4];
  const void* bk = d_in[5];
  const void* Wv = d_in[6];
  const void* bv = d_in[7];

  const size_t SZ = (size_t)B_ * Nn * Cc;  // 4M elems = 8MB bf16 per region
  // ws: [flag 1KB][lbuf 256KB][Xtq 8MB][Qt 8MB][Kt 8MB]  (~24.3MB)
  // d_out (16MB when fp32): Xtk scratch (lower 8MB) + Wb (upper) until the
  // gemms finish, then zeroed and reused as the fp32 O accumulator.
  int*   flag = (int*)d_ws;
  float* lbuf = (float*)((char*)d_ws + 1024);
  bf16*  Xtq  = (bf16*)((char*)d_ws + 1024 + 262144);
  bf16*  Qt   = Xtq + SZ;
  bf16*  Kt   = Qt + SZ;
  bf16*  Xtk  = (bf16*)d_out;                     // dead before zero_ws
  bf16*  Vh   = Xtq;                              // V e-major (B,E,N)
  bf16*  Wb   = (bf16*)((char*)d_out + 8 * 1024 * 1024);
  bf16* Wqb = Wb,            *Wkb = Wb + WSEG,    *Wvb = Wb + 2 * WSEG;
  bf16* bqb = Wb + 3 * WSEG, *bkb = bqb + 512,    *bvb = bqb + 1024;

  detect_dtype<<<1, 64, 0, stream>>>((const unsigned short*)Wq, flag);
  wcvt<<<(WTOT / 8 + 255) / 256, 256, 0, stream>>>(
      (const float*)Wq, (const float*)Wk, (const float*)Wv,
      (const float*)bq, (const float*)bk, (const float*)bv, Wb, flag);
  transpose_k<<<dim3(64, 8, 4), 256, 0, stream>>>(q, k, Xtq, Xtk, flag);
  gemm3<<<dim3(32, 8, 6), 256, 0, stream>>>(
      Xtq, Xtk, Wq, Wqb, Wk, Wkb, Wv, Wvb,
      bq, bqb, bk, bkb, bv, bvb, Qt, Kt, Vh, flag);
  zero_ws<<<4160, 256, 0, stream>>>((float*)d_out, lbuf, flag);
  attn<<<dim3(64, NH, B_), 256, 0, stream>>>(Qt, Kt, Vh, d_out, lbuf, flag);
  normalize<<<4096, 256, 0, stream>>>((float*)d_out, lbuf, flag);
}

// Round 10
// 222.247 us; speedup vs baseline: 1.3077x; 1.3077x over previous
//
#include <hip/hip_runtime.h>

// CausalAttention2d: B=2, C=512, H=W=64 (N=4096 tokens), E=512, nh=8, hd=64.
// Inputs fp32 (runtime-detected; bf16 path kept defensively). Pipeline:
//   detect -> wcvt -> transpose -> gemmQK -> gemmV -> flash attn.
// Round 10: fix r9's replay-divergence. Root cause: r8/r9 fused all three
// projections into ONE launch while Vh aliases Xtq -> V-blocks wrote Xtq
// while Q-blocks still read it (block-schedule-dependent race; tripwire
// caught it). Fix: split along the dependency edge - gemm3(zoff=0) does
// Q+K, gemm3(zoff=4) does V; same-stream launches serialize. Also swap
// inline-asm v_exp_f32 for __builtin_amdgcn_exp2f (same 1 instruction,
// compiler-managed TRANS hazards). r9's VALU-diet softmax kept:
// P = 2^s (shift cancels in O/l), uniform diag branch, manual pair-pack.

typedef __bf16 bf16;
typedef __attribute__((ext_vector_type(8))) __bf16 bf16x8;
typedef __attribute__((ext_vector_type(4))) float floatx4;

#define B_ 2
#define Cc 512
#define Nn 4096
#define Ee 512
#define NH 8
#define HD 64

#define QSCALE 0.1803368801111204f   // log2(e)/8, folded into Q

// ---------------------------------------------------------------- detector
__global__ __launch_bounds__(64) void detect_dtype(
    const unsigned short* __restrict__ w, int* __restrict__ flag) {
  bool bad = false;
#pragma unroll
  for (int i = 0; i < 16; ++i) {
    unsigned u = w[threadIdx.x * 16 + i];
    float v = __uint_as_float(u << 16);
    bad |= !(v > -1024.f && v < 1024.f);  // catches big / inf / NaN
  }
  unsigned long long b = __ballot(bad);
  if (threadIdx.x == 0) *flag = (b != 0ull) ? 1 : 0;
}

// ---------------------------------------------------------------- wcvt
#define WSEG 262144          // 512*512
#define WTOT 787968          // 3*WSEG + 3*512
__global__ __launch_bounds__(256) void wcvt(
    const float* __restrict__ Wq, const float* __restrict__ Wk,
    const float* __restrict__ Wv, const float* __restrict__ bq,
    const float* __restrict__ bk, const float* __restrict__ bv,
    bf16* __restrict__ out, const int* __restrict__ flagp) {
  if (!*flagp) return;
  int idx = (blockIdx.x * 256 + threadIdx.x) * 8;
  if (idx >= WTOT) return;
  const float* src;
  int off;
  if (idx < WSEG)            { src = Wq; off = idx; }
  else if (idx < 2 * WSEG)   { src = Wk; off = idx - WSEG; }
  else if (idx < 3 * WSEG)   { src = Wv; off = idx - 2 * WSEG; }
  else if (idx < 3 * WSEG + 512)  { src = bq; off = idx - 3 * WSEG; }
  else if (idx < 3 * WSEG + 1024) { src = bk; off = idx - 3 * WSEG - 512; }
  else                            { src = bv; off = idx - 3 * WSEG - 1024; }
  float4 a = *(const float4*)(src + off);
  float4 c = *(const float4*)(src + off + 4);
  union { bf16 h[8]; bf16x8 v; } u;
  u.h[0] = (bf16)a.x; u.h[1] = (bf16)a.y; u.h[2] = (bf16)a.z; u.h[3] = (bf16)a.w;
  u.h[4] = (bf16)c.x; u.h[5] = (bf16)c.y; u.h[6] = (bf16)c.z; u.h[7] = (bf16)c.w;
  *(bf16x8*)(out + idx) = u.v;
}

// load 8 consecutive elements as bf16x8 from bf16 (f32=0) or fp32 (f32=1).
__device__ __forceinline__ bf16x8 load8e(const void* base, size_t eidx, int f32) {
  if (!f32) return *(const bf16x8*)((const bf16*)base + eidx);
  const float* f = (const float*)base + eidx;
  float4 a = *(const float4*)f;
  float4 c = *(const float4*)(f + 4);
  union { bf16 h[8]; bf16x8 v; } u;
  u.h[0] = (bf16)a.x; u.h[1] = (bf16)a.y; u.h[2] = (bf16)a.z; u.h[3] = (bf16)a.w;
  u.h[4] = (bf16)c.x; u.h[5] = (bf16)c.y; u.h[6] = (bf16)c.z; u.h[7] = (bf16)c.w;
  return u.v;
}

// ---------------------------------------------------------------- transpose
__global__ __launch_bounds__(256) void transpose_k(
    const void* __restrict__ X0, const void* __restrict__ X1,
    bf16* __restrict__ T0, bf16* __restrict__ T1,
    const int* __restrict__ flagp) {
  const int f32 = *flagp;
  __shared__ __align__(16) bf16 T[64 * 64];
  const int z = blockIdx.z;
  const int bb = z & 1;
  const void* src = (z >> 1) ? X1 : X0;
  bf16* dst = (z >> 1) ? T1 : T0;
  const int n0 = blockIdx.x * 64, c0 = blockIdx.y * 64;
  const int t = threadIdx.x;
  const size_t sbase = ((size_t)bb * Cc + c0) * (size_t)Nn + n0;

#pragma unroll
  for (int it = 0; it < 2; ++it) {
    int task = t + it * 256;            // 512 tasks: 64 c-rows x 8 n-granules
    int crow = task >> 3, gr = task & 7;
    bf16x8 v = load8e(src, sbase + (size_t)crow * Nn + gr * 8, f32);
    int slot = gr ^ (crow & 7);
    *(bf16x8*)&T[crow * 64 + slot * 8] = v;
  }
  __syncthreads();
  const int nrow = t & 63, cp = t >> 6;
  bf16* db = dst + ((size_t)bb * Nn + n0 + nrow) * Cc + c0;
#pragma unroll
  for (int it = 0; it < 2; ++it) {
    int cg = cp * 2 + it;               // c-granule 0..7
    union { bf16 h[8]; bf16x8 v; } u;
#pragma unroll
    for (int j = 0; j < 8; ++j) {
      int c = cg * 8 + j;
      int slot = (nrow >> 3) ^ (c & 7);
      u.h[j] = T[c * 64 + slot * 8 + (nrow & 7)];
    }
    *(bf16x8*)(db + cg * 8) = u.v;
  }
}

// ---------------------------------------------------------------- gemm3
// Q/K/V projection; (blockIdx.z + zoff): 0,1 = Q(b); 2,3 = K(b); 4,5 = V(b).
// Launched in two pieces (zoff=0 grid z=4 for Q+K; zoff=4 grid z=2 for V)
// because Vh ALIASES Xtq - one fused launch races V-writes vs Q-reads.
// Out[m][n] = (sum_k A[m][k]*Bt[n][k] + bias) * scaleOut, K=512.
// Double-buffered LDS, one barrier per K-step, register prefetch.
__global__ __launch_bounds__(256) void gemm3(
    const bf16* __restrict__ Xtq, const bf16* __restrict__ Xtk,
    const void* __restrict__ Wq0, const bf16* __restrict__ Wqb,
    const void* __restrict__ Wk0, const bf16* __restrict__ Wkb,
    const void* __restrict__ Wv0, const bf16* __restrict__ Wvb,
    const void* __restrict__ bq0, const bf16* __restrict__ bqb,
    const void* __restrict__ bk0, const bf16* __restrict__ bkb,
    const void* __restrict__ bv0, const bf16* __restrict__ bvb,
    bf16* __restrict__ Qt, bf16* __restrict__ Kt, bf16* __restrict__ Vh,
    int zoff, const int* __restrict__ flagp) {
  const int f32 = *flagp;
  const int z = (int)blockIdx.z + zoff;
  const int op = z >> 1, b = z & 1;
  const bf16 *A, *Bt, *bias;
  bf16* Out;
  long sAb, sBb, sOb;
  int Nq, biasOnM, m0, n0;
  float scaleOut;
  if (op == 0) {
    A = Xtq; sAb = (long)Nn * Cc;
    Bt = f32 ? Wqb : (const bf16*)Wq0; sBb = 0;
    bias = f32 ? bqb : (const bf16*)bq0;
    Out = Qt; sOb = (long)Nn * Ee; Nq = Ee; biasOnM = 0; scaleOut = QSCALE;
    m0 = blockIdx.x * 128; n0 = blockIdx.y * 64;
  } else if (op == 1) {
    A = Xtk; sAb = (long)Nn * Cc;
    Bt = f32 ? Wkb : (const bf16*)Wk0; sBb = 0;
    bias = f32 ? bkb : (const bf16*)bk0;
    Out = Kt; sOb = (long)Nn * Ee; Nq = Ee; biasOnM = 0; scaleOut = 1.0f;
    m0 = blockIdx.x * 128; n0 = blockIdx.y * 64;
  } else {
    A = f32 ? Wvb : (const bf16*)Wv0; sAb = 0;
    Bt = Xtk; sBb = (long)Nn * Cc;
    bias = f32 ? bvb : (const bf16*)bv0;
    Out = Vh; sOb = (long)Ee * Nn; Nq = Nn; biasOnM = 1; scaleOut = 1.0f;
    m0 = (blockIdx.x >> 3) * 128;
    n0 = (blockIdx.y * 8 + (blockIdx.x & 7)) * 64;
  }
  constexpr int K = 512;
  constexpr int SA = 40;
  __shared__ __align__(16) bf16 As[2][128 * SA];
  __shared__ __align__(16) bf16 Bs[2][64 * SA];
  const int tid = threadIdx.x;
  const int lane = tid & 63, wave = tid >> 6;
  const int quad = lane >> 4, lm = lane & 15;
  const bf16* Ab = A + (size_t)b * sAb;
  const bf16* Bb = Bt + (size_t)b * sBb;
  bf16* Ob = Out + (size_t)b * sOb;

  const int arow = tid >> 2, ag = tid & 3;

  floatx4 acc[2][4];
#pragma unroll
  for (int i = 0; i < 2; ++i)
#pragma unroll
    for (int j = 0; j < 4; ++j) acc[i][j] = (floatx4){0.f, 0.f, 0.f, 0.f};

  bf16x8 a0 = *(const bf16x8*)(Ab + (size_t)(m0 + arow) * K + ag * 8);
  bf16x8 a1 = *(const bf16x8*)(Ab + (size_t)(m0 + 64 + arow) * K + ag * 8);
  bf16x8 b0 = *(const bf16x8*)(Bb + (size_t)(n0 + arow) * K + ag * 8);
  *(bf16x8*)&As[0][arow * SA + ag * 8] = a0;
  *(bf16x8*)&As[0][(64 + arow) * SA + ag * 8] = a1;
  *(bf16x8*)&Bs[0][arow * SA + ag * 8] = b0;
  __syncthreads();

  for (int kk = 0; kk < 16; ++kk) {
    const int c = kk & 1;
    const bool more = kk < 15;
    if (more) {
      int k0 = (kk + 1) * 32;
      a0 = *(const bf16x8*)(Ab + (size_t)(m0 + arow) * K + k0 + ag * 8);
      a1 = *(const bf16x8*)(Ab + (size_t)(m0 + 64 + arow) * K + k0 + ag * 8);
      b0 = *(const bf16x8*)(Bb + (size_t)(n0 + arow) * K + k0 + ag * 8);
    }
    bf16x8 af[2], bfr[4];
#pragma unroll
    for (int mf = 0; mf < 2; ++mf) {
      int r = wave * 32 + mf * 16 + lm;
      af[mf] = *(const bf16x8*)&As[c][r * SA + quad * 8];
    }
#pragma unroll
    for (int nf = 0; nf < 4; ++nf) {
      int r = nf * 16 + lm;
      bfr[nf] = *(const bf16x8*)&Bs[c][r * SA + quad * 8];
    }
    if (more) {
      *(bf16x8*)&As[c ^ 1][arow * SA + ag * 8] = a0;
      *(bf16x8*)&As[c ^ 1][(64 + arow) * SA + ag * 8] = a1;
      *(bf16x8*)&Bs[c ^ 1][arow * SA + ag * 8] = b0;
    }
#pragma unroll
    for (int mf = 0; mf < 2; ++mf)
#pragma unroll
      for (int nf = 0; nf < 4; ++nf)
        acc[mf][nf] = __builtin_amdgcn_mfma_f32_16x16x32_bf16(
            af[mf], bfr[nf], acc[mf][nf], 0, 0, 0);
    __syncthreads();
  }

#pragma unroll
  for (int mf = 0; mf < 2; ++mf) {
#pragma unroll
    for (int nf = 0; nf < 4; ++nf) {
      int col = n0 + nf * 16 + lm;
      float bn = biasOnM ? 0.f : (float)bias[col];
#pragma unroll
      for (int r = 0; r < 4; ++r) {
        int rowg = m0 + wave * 32 + mf * 16 + quad * 4 + r;
        float bv = biasOnM ? (float)bias[rowg] : bn;
        Ob[(size_t)rowg * Nq + col] = (bf16)((acc[mf][nf][r] + bv) * scaleOut);
      }
    }
  }
}

// single v_exp_f32 with compiler-managed hazards (s in [-13,7]: no guards
// needed; denormal/overflow impossible).
__device__ __forceinline__ float fast_exp2(float x) {
  return __builtin_amdgcn_exp2f(x);
}
// round-half-up bf16 of two floats packed into one u32 (lo = a, hi = b).
__device__ __forceinline__ unsigned pack_bf16_2(float a, float b) {
  unsigned ua = __float_as_uint(a) + 0x8000u;
  unsigned ub = __float_as_uint(b) + 0x8000u;
  return (ua >> 16) | (ub & 0xFFFF0000u);
}

// ---------------------------------------------------------------- attention
// Grid (32, NH, B): p = 31-bx (heavy first). Block = 4 waves x 32 q = 128 q.
// Per 64-key tile: QK with permuted A-rows so S^T per lane = keys
// quad*8+{0..7} (exact 16x16x32 PV B-frag, in-register P); V reads b128;
// rotate-swizzle slot=(gran+row)&7 on SK=72. Double-buffered, register
// prefetch, one barrier per tile. Softmax: P = 2^s (scale cancels in O/l),
// v_exp builtin, uniform diag branch, manual pair-pack.
__global__ __launch_bounds__(256, 2) void attn(
    const bf16* __restrict__ Qt, const bf16* __restrict__ Kt,
    const bf16* __restrict__ Ve, void* __restrict__ Out,
    const int* __restrict__ flagp) {
  const int f32 = *flagp;
  constexpr int SK = 72;
  __shared__ __align__(16) bf16 Ks[2][64 * SK];   // [buf][key][e]
  __shared__ __align__(16) bf16 Vs[2][64 * SK];   // [buf][d][key]
  const int tid = threadIdx.x, lane = tid & 63, w = tid >> 6;
  const int quad = lane >> 4, lm = lane & 15;
  const int b = blockIdx.z, h = blockIdx.y;
  const int p = 31 - (int)blockIdx.x;
  const int Q0 = p * 128;
  const int qbase = Q0 + w * 32;
  const int last = 2 * p + 1;

  // Q B-frags (persistent): qf[qi][ks] = B[e=quad*8+j+ks*32][q=qi*16+lm]
  bf16x8 qf[2][2];
#pragma unroll
  for (int qi = 0; qi < 2; ++qi) {
    const bf16* qp =
        Qt + ((size_t)b * Nn + qbase + qi * 16 + lm) * Ee + h * HD + quad * 8;
    qf[qi][0] = *(const bf16x8*)qp;
    qf[qi][1] = *(const bf16x8*)(qp + 32);
  }
  floatx4 accO[2][4];
#pragma unroll
  for (int qi = 0; qi < 2; ++qi)
#pragma unroll
    for (int df = 0; df < 4; ++df) accO[qi][df] = (floatx4){0.f, 0.f, 0.f, 0.f};
  float lsum[2] = {0.f, 0.f};

  // staging: r0 = tid>>3 in [0,32), g = tid&7; rows r0 and r0+32
  const int r0 = tid >> 3, g = tid & 7;
  const int sslot = ((g + r0) & 7) * 8;           // rotate swizzle
  const bf16* kp0 = Kt + ((size_t)b * Nn + r0) * Ee + h * HD + g * 8;
  const bf16* kp1 = kp0 + (size_t)32 * Ee;
  const bf16* vp0 = Ve + ((size_t)b * Ee + h * HD + r0) * Nn + g * 8;
  const bf16* vp1 = vp0 + (size_t)32 * Nn;

  // QK A-row permutation base: row R = quad*8 + 4*(f&1) + (lm&3) + 32*(f>>1)
  const int rbase = ((lm >> 2) << 3) | (lm & 3);

  // prologue: tile 0 -> buf 0
  bf16x8 ka = *(const bf16x8*)kp0;
  bf16x8 kb = *(const bf16x8*)kp1;
  bf16x8 va = *(const bf16x8*)vp0;
  bf16x8 vb = *(const bf16x8*)vp1;
  kp0 += (size_t)64 * Ee; kp1 += (size_t)64 * Ee;
  vp0 += 64; vp1 += 64;
  *(bf16x8*)&Ks[0][r0 * SK + sslot] = ka;
  *(bf16x8*)&Ks[0][(r0 + 32) * SK + sslot] = kb;
  *(bf16x8*)&Vs[0][r0 * SK + sslot] = va;
  *(bf16x8*)&Vs[0][(r0 + 32) * SK + sslot] = vb;
  __syncthreads();

#pragma unroll 1
  for (int kt = 0; kt <= last; ++kt) {
    const int c = kt & 1;
    const int k0 = kt * 64;
    const bool more = kt < last;
    if (more) {                       // prefetch next tile (hidden under QK)
      ka = *(const bf16x8*)kp0;
      kb = *(const bf16x8*)kp1;
      va = *(const bf16x8*)vp0;
      vb = *(const bf16x8*)vp1;
      kp0 += (size_t)64 * Ee; kp1 += (size_t)64 * Ee;
      vp0 += 64; vp1 += 64;
    }
    const bool skip = k0 > qbase + 31;  // wave-uniform: tile fully masked

    bf16x8 pb[2][2];
    if (!skip) {
      // S^T = K Q^T with permuted A-rows
      floatx4 accS[2][4];
#pragma unroll
      for (int qi = 0; qi < 2; ++qi)
#pragma unroll
        for (int f = 0; f < 4; ++f) accS[qi][f] = (floatx4){0.f, 0.f, 0.f, 0.f};
#pragma unroll
      for (int ks = 0; ks < 2; ++ks)
#pragma unroll
        for (int f = 0; f < 4; ++f) {
          const int R = rbase + ((f & 1) << 2) + ((f >> 1) << 5);
          const int slot = (ks * 4 + quad + R) & 7;
          bf16x8 ak = *(const bf16x8*)&Ks[c][R * SK + slot * 8];
#pragma unroll
          for (int qi = 0; qi < 2; ++qi)
            accS[qi][f] = __builtin_amdgcn_mfma_f32_16x16x32_bf16(
                ak, qf[qi][ks], accS[qi][f], 0, 0, 0);
        }
      // softmax + pack: key = k0 + g2*32 + quad*8 + j; q = qbase+qi*16+lm
      const bool maskt = (k0 + 63 > qbase);
      if (!maskt) {
        // mask-free fast path (vast majority of tiles)
#pragma unroll
        for (int qi = 0; qi < 2; ++qi) {
          float la = 0.f, lb = 0.f;
#pragma unroll
          for (int g2 = 0; g2 < 2; ++g2) {
            union { unsigned pk[4]; bf16x8 v; } u;
#pragma unroll
            for (int jp = 0; jp < 4; ++jp) {
              const int fidx = g2 * 2 + (jp >> 1);
              const int re = (jp & 1) * 2;
              float p0 = fast_exp2(accS[qi][fidx][re]);
              float p1 = fast_exp2(accS[qi][fidx][re + 1]);
              la += p0; lb += p1;
              u.pk[jp] = pack_bf16_2(p0, p1);
            }
            pb[qi][g2] = u.v;
          }
          lsum[qi] += la + lb;
        }
      } else {
        // diagonal tile: per-element causal zeroing
#pragma unroll
        for (int qi = 0; qi < 2; ++qi) {
          const int qg = qbase + qi * 16 + lm;
          float la = 0.f, lb = 0.f;
#pragma unroll
          for (int g2 = 0; g2 < 2; ++g2) {
            union { unsigned pk[4]; bf16x8 v; } u;
#pragma unroll
            for (int jp = 0; jp < 4; ++jp) {
              const int fidx = g2 * 2 + (jp >> 1);
              const int re = (jp & 1) * 2;
              const int key0 = k0 + g2 * 32 + quad * 8 + jp * 2;
              float p0 = fast_exp2(accS[qi][fidx][re]);
              float p1 = fast_exp2(accS[qi][fidx][re + 1]);
              if (key0 > qg) p0 = 0.f;
              if (key0 + 1 > qg) p1 = 0.f;
              la += p0; lb += p1;
              u.pk[jp] = pack_bf16_2(p0, p1);
            }
            pb[qi][g2] = u.v;
          }
          lsum[qi] += la + lb;
        }
      }
    }
    if (more) {                       // stage prefetched tile into other buf
      *(bf16x8*)&Ks[c ^ 1][r0 * SK + sslot] = ka;
      *(bf16x8*)&Ks[c ^ 1][(r0 + 32) * SK + sslot] = kb;
      *(bf16x8*)&Vs[c ^ 1][r0 * SK + sslot] = va;
      *(bf16x8*)&Vs[c ^ 1][(r0 + 32) * SK + sslot] = vb;
    }
    if (!skip) {
      // O^T += V^T P^T at K=32: A[d=df*16+lm][key=g2*32+quad*8+j] (b128)
#pragma unroll
      for (int g2 = 0; g2 < 2; ++g2)
#pragma unroll
        for (int df = 0; df < 4; ++df) {
          const int Rv = df * 16 + lm;
          const int slot = (g2 * 4 + quad + Rv) & 7;
          bf16x8 av = *(const bf16x8*)&Vs[c][Rv * SK + slot * 8];
#pragma unroll
          for (int qi = 0; qi < 2; ++qi)
            accO[qi][df] = __builtin_amdgcn_mfma_f32_16x16x32_bf16(
                av, pb[qi][g2], accO[qi][df], 0, 0, 0);
        }
    }
    __syncthreads();  // buf c reads done everywhere; buf c^1 fully staged
  }

  // l(q) split across the 4 quads -> reduce lanes lm+16k
#pragma unroll
  for (int qi = 0; qi < 2; ++qi) {
    lsum[qi] += __shfl_xor(lsum[qi], 16);
    lsum[qi] += __shfl_xor(lsum[qi], 32);
  }

  // epilogue: accO[qi][df] rows d = df*16+quad*4+r, col q = qbase+qi*16+lm
#pragma unroll
  for (int qi = 0; qi < 2; ++qi) {
    const float inv = 1.0f / lsum[qi];
    const int qg = qbase + qi * 16 + lm;
#pragma unroll
    for (int df = 0; df < 4; ++df) {
#pragma unroll
      for (int r = 0; r < 4; ++r) {
        int d = h * HD + df * 16 + quad * 4 + r;
        size_t off = ((size_t)b * Ee + d) * Nn + qg;
        if (!f32) ((bf16*)Out)[off] = (bf16)(accO[qi][df][r] * inv);
        else      ((float*)Out)[off] = accO[qi][df][r] * inv;
      }
    }
  }
}

// ---------------------------------------------------------------- launch
extern "C" void kernel_launch(void* const* d_in, const int* in_sizes, int n_in,
                              void* d_out, int out_size, void* d_ws,
                              size_t ws_size, hipStream_t stream) {
  const void* q  = d_in[0];
  const void* k  = d_in[1];
  const void* Wq = d_in[2];
  const void* bq = d_in[3];
  const void* Wk = d_in[4];
  const void* bk = d_in[5];
  const void* Wv = d_in[6];
  const void* bv = d_in[7];

  const size_t SZ = (size_t)B_ * Nn * Cc;  // 4M elems = 8MB bf16 per region
  // ws: [flag 1KB][Xtq 8MB][Qt 8MB][Kt 8MB].
  // d_out (16MB when fp32): lower 8MB = Xtk scratch, upper 8MB = bf16 W/bias
  // copies; both dead before attn writes the final output.
  int*  flag = (int*)d_ws;
  bf16* Xtq  = (bf16*)((char*)d_ws + 1024);
  bf16* Qt   = Xtq + SZ;
  bf16* Kt   = Qt + SZ;
  bf16* Xtk  = (bf16*)d_out;
  bf16* Vh   = Xtq;                              // V e-major (B,E,N)
  bf16* Wb   = (bf16*)((char*)d_out + 8 * 1024 * 1024);
  bf16* Wqb = Wb,            *Wkb = Wb + WSEG,    *Wvb = Wb + 2 * WSEG;
  bf16* bqb = Wb + 3 * WSEG, *bkb = bqb + 512,    *bvb = bqb + 1024;

  detect_dtype<<<1, 64, 0, stream>>>((const unsigned short*)Wq, flag);
  wcvt<<<(WTOT / 8 + 255) / 256, 256, 0, stream>>>(
      (const float*)Wq, (const float*)Wk, (const float*)Wv,
      (const float*)bq, (const float*)bk, (const float*)bv, Wb, flag);
  transpose_k<<<dim3(64, 8, 4), 256, 0, stream>>>(q, k, Xtq, Xtk, flag);
  // Q+K projections (read Xtq/Xtk; no aliasing within the launch)
  gemm3<<<dim3(32, 8, 4), 256, 0, stream>>>(
      Xtq, Xtk, Wq, Wqb, Wk, Wkb, Wv, Wvb,
      bq, bqb, bk, bkb, bv, bvb, Qt, Kt, Vh, 0, flag);
  // V projection (writes Vh == Xtq region) - separate launch, serialized
  gemm3<<<dim3(32, 8, 2), 256, 0, stream>>>(
      Xtq, Xtk, Wq, Wqb, Wk, Wkb, Wv, Wvb,
      bq, bqb, bk, bkb, bv, bvb, Qt, Kt, Vh, 4, flag);
  attn<<<dim3(32, NH, B_), 256, 0, stream>>>(Qt, Kt, Vh, d_out, flag);
}